// Round 13
// baseline (197.391 us; speedup 1.0000x reference)
//
#include <hip/hip_runtime.h>
#include <hip/hip_bf16.h>

#define H 768
#define NH 12
#define DH 64
#define LL 8
#define NTOK 16384   // B*S = 8*2048
#define NREL 100
#define NRELP 128    // padded rows for the K/V-table GEMM

typedef __attribute__((ext_vector_type(8))) short short8;
typedef __attribute__((ext_vector_type(4))) float f32x4;

__device__ __forceinline__ float bf2f(ushort u) {
  union { unsigned int i; float f; } v; v.i = ((unsigned int)u) << 16; return v.f;
}
__device__ __forceinline__ float bflo(unsigned int u) {
  union { unsigned int i; float f; } v; v.i = u << 16; return v.f;
}
__device__ __forceinline__ float bfhi(unsigned int u) {
  union { unsigned int i; float f; } v; v.i = u & 0xffff0000u; return v.f;
}
__device__ __forceinline__ ushort f2bf(float f) {
  union { float f; unsigned int i; } v; v.f = f;
  unsigned int x = v.i;
  return (ushort)((x + 0x7fffu + ((x >> 16) & 1u)) >> 16);  // RNE
}
// HW packed f32->bf16 (RNE); lo = S0, hi = S1 [guide T12 recipe, m214v22]
__device__ __forceinline__ unsigned int cvt_pk_bf16(float lo, float hi) {
  unsigned int r;
  asm("v_cvt_pk_bf16_f32 %0, %1, %2" : "=v"(r) : "v"(lo), "v"(hi));
  return r;
}

// ---------- prep: z<4 -> weight transpose [H][H] f32->bf16; z=4 -> rel cvt
__global__ __launch_bounds__(256) void prep_kernel(
    const float* __restrict__ s0, ushort* __restrict__ d0,
    const float* __restrict__ s1, ushort* __restrict__ d1,
    const float* __restrict__ s2, ushort* __restrict__ d2,
    const float* __restrict__ s3, ushort* __restrict__ d3,
    const float* __restrict__ rel, ushort* __restrict__ RelB) {
  if (blockIdx.z == 4) {
    int b = blockIdx.y * 24 + blockIdx.x;
    if (b < 96) {                                  // 96*1024 = NRELP*H
      int i = (b * 256 + threadIdx.x) * 4;         // 4-chunk stays within a row
      int row = i / H;
      ushort4 o = {0, 0, 0, 0};
      if (row < NREL) {
        float4 v = *(const float4*)(rel + i);
        o.x = f2bf(v.x); o.y = f2bf(v.y); o.z = f2bf(v.z); o.w = f2bf(v.w);
      }
      *(ushort4*)(RelB + i) = o;
    }
    return;
  }
  const float* src; ushort* dst;
  switch (blockIdx.z) {
    case 0:  src = s0; dst = d0; break;
    case 1:  src = s1; dst = d1; break;
    case 2:  src = s2; dst = d2; break;
    default: src = s3; dst = d3; break;
  }
  __shared__ float tile[32][33];
  int bx = blockIdx.x * 32, by = blockIdx.y * 32;
  int tx = threadIdx.x & 31, ty = threadIdx.x >> 5;  // ty 0..7
  #pragma unroll
  for (int i = 0; i < 32; i += 8)
    tile[ty + i][tx] = src[(size_t)(by + ty + i) * H + bx + tx];
  __syncthreads();
  #pragma unroll
  for (int i = 0; i < 32; i += 8)
    dst[(size_t)(bx + ty + i) * H + by + tx] = f2bf(tile[tx][ty + i]);
}

// ---------------------------------------------------------- 64-row GEMM core
// A-panel (64x768 bf16) resident in LDS (Xs, 96 KB, 16B-chunk swizzle ^(r&7));
// per-K-step staging touches only the L2-hot weight panel (Bst, 32 KB).
// 512 threads = 8 waves (2 row x 4 col), wave tile 32x64, acc[2][4].
__device__ __forceinline__ void gload_lds16(const void* g, void* l) {
  __builtin_amdgcn_global_load_lds(
      (const __attribute__((address_space(1))) unsigned int*)g,
      (__attribute__((address_space(3))) unsigned int*)l, 16, 0, 0);
}

// stage bf16 A-panel (src pre-swizzled so linear LDS + swizzled read agree)
__device__ __forceinline__ void stage_A_bf16(char* Xs, const ushort* A, int row0) {
  const int tid = threadIdx.x;
  #pragma unroll
  for (int i = 0; i < 12; ++i) {
    int c = tid + i * 512;
    int r = c / 96, p = c - r * 96;
    gload_lds16(A + (size_t)(row0 + r) * H + ((p ^ (r & 7)) << 3), Xs + (size_t)c * 16);
  }
}

// stage f32 A-panel with fused cvt (reg-staged, so write swizzled directly)
__device__ __forceinline__ void stage_A_f32cvt(char* Xs, const float* X, int row0) {
  const int tid = threadIdx.x;
  #pragma unroll
  for (int i = 0; i < 12; ++i) {
    int c = tid + i * 512;
    int r = c / 96, p = c - r * 96;
    const float* src = X + (size_t)(row0 + r) * H + p * 8;
    float4 f0 = *(const float4*)src;
    float4 f1 = *(const float4*)(src + 4);
    uint4 w;
    w.x = cvt_pk_bf16(f0.x, f0.y); w.y = cvt_pk_bf16(f0.z, f0.w);
    w.z = cvt_pk_bf16(f1.x, f1.y); w.w = cvt_pk_bf16(f1.z, f1.w);
    *(uint4*)(Xs + r * 1536 + ((p ^ (r & 7)) * 16)) = w;
  }
}

// K-loop over 768 (BK=64). Caller declares f32x4 acc[2][4] and tid/wr/wc/lr/lk.
#define CHUNK_GEMM(BT, colbase)                                                \
  for (int t = 0; t < 12; ++t) {                                               \
    const int k0 = t * 64;                                                     \
    _Pragma("unroll")                                                          \
    for (int i = 0; i < 4; ++i) {                                              \
      int c = tid + i * 512; int rr = c >> 3, ss = c & 7; int g = ss ^ (rr & 7); \
      gload_lds16((BT) + (size_t)((colbase) + rr) * H + k0 + g * 8,            \
                  Bst + (size_t)c * 16);                                       \
    }                                                                          \
    __syncthreads();                                                           \
    _Pragma("unroll")                                                          \
    for (int kk = 0; kk < 2; ++kk) {                                           \
      short8 af[2], bfr[4];                                                    \
      _Pragma("unroll")                                                        \
      for (int m = 0; m < 2; ++m) {                                            \
        int row = wr * 32 + m * 16 + lr;                                       \
        int ch = (k0 >> 3) + (kk << 2) + lk;                                   \
        af[m] = *(const short8*)(Xs + row * 1536 + ((ch ^ (row & 7)) * 16));   \
      }                                                                        \
      const int sw = (((kk << 2) | lk) ^ (lr & 7)) * 16;                       \
      _Pragma("unroll")                                                        \
      for (int nn = 0; nn < 4; ++nn)                                           \
        bfr[nn] = *(const short8*)(Bst + (wc * 64 + nn * 16 + lr) * 128 + sw); \
      _Pragma("unroll")                                                        \
      for (int m = 0; m < 2; ++m)                                              \
        _Pragma("unroll")                                                      \
        for (int nn = 0; nn < 4; ++nn)                                         \
          acc[m][nn] = __builtin_amdgcn_mfma_f32_16x16x32_bf16(               \
              af[m], bfr[nn], acc[m][nn], 0, 0, 0);                            \
    }                                                                          \
    __syncthreads();                                                           \
  }

// epilogue: C/D layout col = lane&15, row = (lane>>4)*4 + j [verified m89/m91]
#define CHUNK_EPI_GLOBAL(COUT, BIAS, colbase, row0)                            \
  _Pragma("unroll")                                                            \
  for (int m = 0; m < 2; ++m)                                                  \
    _Pragma("unroll")                                                          \
    for (int nn = 0; nn < 4; ++nn) {                                           \
      int col = (colbase) + wc * 64 + nn * 16 + lr;                            \
      float b = (BIAS)[col];                                                   \
      _Pragma("unroll")                                                        \
      for (int j = 0; j < 4; ++j) {                                            \
        int row = (row0) + wr * 32 + m * 16 + lk * 4 + j;                      \
        (COUT)[(size_t)row * H + col] = f2bf(acc[m][nn][j] + b);               \
      }                                                                        \
    }

// -------------------------- K/V tables: RelB[128x768] @ {WkT,WvT}^T, 12 blocks
__global__ __launch_bounds__(512, 1) void kv12_kernel(
    const ushort* __restrict__ RelB,
    const ushort* __restrict__ WkT, const float* __restrict__ bk, ushort* __restrict__ Ktab,
    const ushort* __restrict__ WvT, const float* __restrict__ bv, ushort* __restrict__ Vtab) {
  __shared__ char lds[131072];
  char* Xs = lds;            // 96 KB
  char* Bst = lds + 98304;   // 32 KB
  const int tid = threadIdx.x;
  const int wave = tid >> 6, lane = tid & 63;
  const int wr = wave >> 2, wc = wave & 3;
  const int lr = lane & 15, lk = lane >> 4;
  int bb = blockIdx.x;                  // 0..11
  const ushort* Bt; const float* bias; ushort* Cout;
  if (bb < 6) { Bt = WkT; bias = bk; Cout = Ktab; }
  else        { Bt = WvT; bias = bv; Cout = Vtab; bb -= 6; }
  const int mb = bb / 3, nb = bb % 3;
  const int row0 = mb * 64;
  stage_A_bf16(Xs, RelB, row0);
  __syncthreads();
  {
    f32x4 acc[2][4];
    #pragma unroll
    for (int m = 0; m < 2; ++m)
      #pragma unroll
      for (int nn = 0; nn < 4; ++nn) acc[m][nn] = (f32x4)(0.f);
    CHUNK_GEMM(Bt, nb * 256)
    CHUNK_EPI_GLOBAL(Cout, bias, nb * 256, row0)
  }
}

// --------------------------------------------------------------- mega kernel
// Per 64-token block: X f32->bf16->LDS once; 3x(Q-GEMM chunk -> Qc LDS ->
// attn for 4 heads -> Ctx global); restage Ctx (L2-hot, own rows); 3x OutProj
// chunk -> OP global. A-operand never staged from HBM per-K-step.
__global__ __launch_bounds__(512, 1) void mega_kernel(
    const float* __restrict__ X,
    const ushort* __restrict__ WqT, const float* __restrict__ bq,
    const ushort* __restrict__ WoT, const float* __restrict__ bo,
    const ushort* __restrict__ Ktab, const ushort* __restrict__ Vtab,
    const int* __restrict__ graph, const int* __restrict__ relid,
    ushort* __restrict__ Ctx, ushort* __restrict__ OP) {
  __shared__ char lds[131072];
  char* Xs = lds;            // 96 KB: X panel, later Ctx panel
  char* Bst = lds + 98304;   // 32 KB: B stage, doubles as Qc between phases
  const int tid = threadIdx.x;
  const int blk = blockIdx.x;                 // 0..255
  const int wg = (blk & 7) * 32 + (blk >> 3); // bijective XCD swizzle
  const int tok0 = wg * 64;
  const int wave = tid >> 6, lane = tid & 63;
  const int wr = wave >> 2, wc = wave & 3;
  const int lr = lane & 15, lk = lane >> 4;

  // phase 0: X panel -> bf16 -> Xs
  stage_A_f32cvt(Xs, X, tok0);
  __syncthreads();

  // phase 1: 3 x (Q chunk -> attn for its 4 heads)
  for (int n = 0; n < 3; ++n) {
    const int col0 = n * 256;
    {
      f32x4 acc[2][4];
      #pragma unroll
      for (int m = 0; m < 2; ++m)
        #pragma unroll
        for (int nn = 0; nn < 4; ++nn) acc[m][nn] = (f32x4)(0.f);
      CHUNK_GEMM(WqT, col0)
      // write Q chunk (+bq) to Qc (=Bst region), row t: 512 B, chunk swizzle ^(t&7)
      #pragma unroll
      for (int m = 0; m < 2; ++m)
        #pragma unroll
        for (int nn = 0; nn < 4; ++nn) {
          int colc = wc * 64 + nn * 16 + lr;
          float b = bq[col0 + colc];
          int cpos = colc >> 3;
          #pragma unroll
          for (int j = 0; j < 4; ++j) {
            int row = wr * 32 + m * 16 + lk * 4 + j;
            *(ushort*)(Bst + row * 512 + ((cpos ^ (row & 7)) * 16) + (colc & 7) * 2)
                = f2bf(acc[m][nn][j] + b);
          }
        }
    }
    __syncthreads();
    // attn: thread tid<256 handles pair (t = tid>>2, head = 4n + (tid&3))
    if (tid < 256) {
      const int t = tid >> 2, hh = tid & 3;
      const int h = n * 4 + hh;
      const int gtok = tok0 + t;
      uint4 qw[8];
      #pragma unroll
      for (int k = 0; k < 8; ++k)
        qw[k] = *(const uint4*)(Bst + t * 512 + ((((hh << 3) + k) ^ (t & 7)) * 16));
      const int4* gp = (const int4*)(graph + (size_t)gtok * LL);
      const int4* rp = (const int4*)(relid + (size_t)gtok * LL);
      int4 ga = gp[0], gb = gp[1];
      int4 ra = rp[0], rb = rp[1];
      int gs[8] = {ga.x, ga.y, ga.z, ga.w, gb.x, gb.y, gb.z, gb.w};
      int rid[8] = {ra.x, ra.y, ra.z, ra.w, rb.x, rb.y, rb.z, rb.w};
      size_t koff[8];
      #pragma unroll
      for (int l = 0; l < 8; ++l) {
        int r = rid[l] < 0 ? 0 : rid[l];
        koff[l] = (size_t)r * H + h * DH;
      }
      float s[8];
      #pragma unroll
      for (int l = 0; l < 8; ++l) s[l] = 0.f;
      #pragma unroll
      for (int j = 0; j < 8; ++j) {
        float qf[8];
        qf[0] = bflo(qw[j].x); qf[1] = bfhi(qw[j].x);
        qf[2] = bflo(qw[j].y); qf[3] = bfhi(qw[j].y);
        qf[4] = bflo(qw[j].z); qf[5] = bfhi(qw[j].z);
        qf[6] = bflo(qw[j].w); qf[7] = bfhi(qw[j].w);
        #pragma unroll
        for (int l = 0; l < 8; ++l) {
          uint4 kw = *(const uint4*)(Ktab + koff[l] + j * 8);
          s[l] += qf[0] * bflo(kw.x) + qf[1] * bfhi(kw.x)
                + qf[2] * bflo(kw.y) + qf[3] * bfhi(kw.y)
                + qf[4] * bflo(kw.z) + qf[5] * bfhi(kw.z)
                + qf[6] * bflo(kw.w) + qf[7] * bfhi(kw.w);
        }
      }
      #pragma unroll
      for (int l = 0; l < 8; ++l)
        s[l] = (gs[l] != -1) ? s[l] * 0.125f : -10000.0f;
      float mx = s[0];
      #pragma unroll
      for (int l = 1; l < 8; ++l) mx = fmaxf(mx, s[l]);
      float p[8], den = 0.f;
      #pragma unroll
      for (int l = 0; l < 8; ++l) { p[l] = __expf(s[l] - mx); den += p[l]; }
      float inv = 1.f / den;
      #pragma unroll
      for (int l = 0; l < 8; ++l) p[l] *= inv;
      ushort* cp = Ctx + (size_t)gtok * H + h * DH;
      #pragma unroll
      for (int j = 0; j < 8; ++j) {
        float a[8];
        #pragma unroll
        for (int d = 0; d < 8; ++d) a[d] = 0.f;
        #pragma unroll
        for (int l = 0; l < 8; ++l) {
          uint4 vw = *(const uint4*)(Vtab + koff[l] + j * 8);
          a[0] += p[l] * bflo(vw.x); a[1] += p[l] * bfhi(vw.x);
          a[2] += p[l] * bflo(vw.y); a[3] += p[l] * bfhi(vw.y);
          a[4] += p[l] * bflo(vw.z); a[5] += p[l] * bfhi(vw.z);
          a[6] += p[l] * bflo(vw.w); a[7] += p[l] * bfhi(vw.w);
        }
        short8 o;
        #pragma unroll
        for (int d = 0; d < 8; ++d) o[d] = (short)f2bf(a[d]);
        *(short8*)(cp + j * 8) = o;
      }
    }
    __syncthreads();
  }

  // phase 2: restage Ctx (own rows, L2-hot) and OutProj
  stage_A_bf16(Xs, Ctx, tok0);
  __syncthreads();
  for (int n = 0; n < 3; ++n) {
    const int col0 = n * 256;
    {
      f32x4 acc[2][4];
      #pragma unroll
      for (int m = 0; m < 2; ++m)
        #pragma unroll
        for (int nn = 0; nn < 4; ++nn) acc[m][nn] = (f32x4)(0.f);
      CHUNK_GEMM(WoT, col0)
      CHUNK_EPI_GLOBAL(OP, bo, col0, tok0)
    }
  }
}

// ------------------------------------- residual + LayerNorm (192 thr, float4)
__global__ __launch_bounds__(192) void ln_kernel(
    const float* __restrict__ text, const ushort* __restrict__ op,
    const float* __restrict__ gamma, const float* __restrict__ beta,
    float* __restrict__ out) {
  int t = blockIdx.x;
  int c0 = threadIdx.x * 4;
  float4 tv = *(const float4*)(text + (size_t)t * H + c0);
  ushort4 ov = *(const ushort4*)(op + (size_t)t * H + c0);
  float x0 = tv.x + bf2f(ov.x), x1 = tv.y + bf2f(ov.y);
  float x2 = tv.z + bf2f(ov.z), x3 = tv.w + bf2f(ov.w);
  float s = x0 + x1 + x2 + x3;
  float s2 = x0 * x0 + x1 * x1 + x2 * x2 + x3 * x3;
  #pragma unroll
  for (int off = 32; off > 0; off >>= 1) {
    s  += __shfl_xor(s, off, 64);
    s2 += __shfl_xor(s2, off, 64);
  }
  __shared__ float red[2][3];
  int wave = threadIdx.x >> 6, lane = threadIdx.x & 63;
  if (lane == 0) { red[0][wave] = s; red[1][wave] = s2; }
  __syncthreads();
  s  = red[0][0] + red[0][1] + red[0][2];
  s2 = red[1][0] + red[1][1] + red[1][2];
  float mu = s * (1.f / H);
  float var = s2 * (1.f / H) - mu * mu;
  float rs = rsqrtf(var + 1e-5f);
  float4 g4 = *(const float4*)(gamma + c0);
  float4 b4 = *(const float4*)(beta + c0);
  float4 o4;
  o4.x = (x0 - mu) * rs * g4.x + b4.x;
  o4.y = (x1 - mu) * rs * g4.y + b4.y;
  o4.z = (x2 - mu) * rs * g4.z + b4.z;
  o4.w = (x3 - mu) * rs * g4.w + b4.w;
  *(float4*)(out + (size_t)t * H + c0) = o4;
}

// ---------------------------------------------------------------------- driver
extern "C" void kernel_launch(void* const* d_in, const int* in_sizes, int n_in,
                              void* d_out, int out_size, void* d_ws, size_t ws_size,
                              hipStream_t stream) {
  const float* text      = (const float*)d_in[0];
  const int*   graph     = (const int*)d_in[1];
  const int*   relid     = (const int*)d_in[2];
  const float* rel_table = (const float*)d_in[3];
  const float* Wq = (const float*)d_in[4];  const float* bq = (const float*)d_in[5];
  const float* Wk = (const float*)d_in[6];  const float* bk = (const float*)d_in[7];
  const float* Wv = (const float*)d_in[8];  const float* bv = (const float*)d_in[9];
  const float* Wo = (const float*)d_in[10]; const float* bo = (const float*)d_in[11];
  const float* gamma = (const float*)d_in[12];
  const float* beta  = (const float*)d_in[13];
  float* out = (float*)d_out;
  char* ws = (char*)d_ws;

  const size_t TOKH = (size_t)NTOK * H;           // 12,582,912
  size_t off = 0;
  ushort* Ctx  = (ushort*)(ws + off); off += TOKH * 2;             // attn out
  ushort* Qbf  = (ushort*)(ws + off); off += TOKH * 2;             // OutProj out
  ushort* WqT  = (ushort*)(ws + off); off += (size_t)H * H * 2;
  ushort* WoT  = (ushort*)(ws + off); off += (size_t)H * H * 2;
  ushort* WkT  = (ushort*)(ws + off); off += (size_t)H * H * 2;
  ushort* WvT  = (ushort*)(ws + off); off += (size_t)H * H * 2;
  ushort* RelB = (ushort*)(ws + off); off += (size_t)NRELP * H * 2;
  ushort* Ktab = (ushort*)(ws + off); off += (size_t)NRELP * H * 2;
  ushort* Vtab = (ushort*)(ws + off); off += (size_t)NRELP * H * 2;

  // 1) weight transposes + rel_table cvt
  prep_kernel<<<dim3(24, 24, 5), 256, 0, stream>>>(
      Wq, WqT, Wo, WoT, Wk, WkT, Wv, WvT, rel_table, RelB);
  // 2) K/V tables (12 blocks)
  kv12_kernel<<<12, 512, 0, stream>>>(RelB, WkT, bk, Ktab, WvT, bv, Vtab);
  // 3) fused Q-GEMM + attention + OutProj per 64-token block
  mega_kernel<<<256, 512, 0, stream>>>(
      text, WqT, bq, WoT, bo, Ktab, Vtab, graph, relid, Ctx, Qbf);
  // 4) residual + LayerNorm
  ln_kernel<<<NTOK, 192, 0, stream>>>(text, Qbf, gamma, beta, out);
}

// Round 14
// 165.518 us; speedup vs baseline: 1.1926x; 1.1926x over previous
//
#include <hip/hip_runtime.h>
#include <hip/hip_bf16.h>

#define H 768
#define NH 12
#define DH 64
#define LL 8
#define NTOK 16384   // B*S = 8*2048
#define NREL 100
#define NRELP 128    // padded rows for the K/V-table GEMM

typedef __attribute__((ext_vector_type(8))) short short8;
typedef __attribute__((ext_vector_type(4))) float f32x4;

__device__ __forceinline__ float bf2f(ushort u) {
  union { unsigned int i; float f; } v; v.i = ((unsigned int)u) << 16; return v.f;
}
__device__ __forceinline__ float bflo(unsigned int u) {
  union { unsigned int i; float f; } v; v.i = u << 16; return v.f;
}
__device__ __forceinline__ float bfhi(unsigned int u) {
  union { unsigned int i; float f; } v; v.i = u & 0xffff0000u; return v.f;
}
__device__ __forceinline__ ushort f2bf(float f) {
  union { float f; unsigned int i; } v; v.f = f;
  unsigned int x = v.i;
  return (ushort)((x + 0x7fffu + ((x >> 16) & 1u)) >> 16);  // RNE
}
// HW packed f32->bf16 (RNE); lo = S0, hi = S1 [guide T12 recipe, m214v22]
__device__ __forceinline__ unsigned int cvt_pk_bf16(float lo, float hi) {
  unsigned int r;
  asm("v_cvt_pk_bf16_f32 %0, %1, %2" : "=v"(r) : "v"(lo), "v"(hi));
  return r;
}

// ---------- prep: z<4 -> weight transpose [H][H] f32->bf16; z=4 -> rel cvt
__global__ __launch_bounds__(256) void prep_kernel(
    const float* __restrict__ s0, ushort* __restrict__ d0,
    const float* __restrict__ s1, ushort* __restrict__ d1,
    const float* __restrict__ s2, ushort* __restrict__ d2,
    const float* __restrict__ s3, ushort* __restrict__ d3,
    const float* __restrict__ rel, ushort* __restrict__ RelB) {
  if (blockIdx.z == 4) {
    int b = blockIdx.y * 24 + blockIdx.x;
    if (b < 96) {                                  // 96*1024 = NRELP*H
      int i = (b * 256 + threadIdx.x) * 4;         // 4-chunk stays within a row
      int row = i / H;
      ushort4 o = {0, 0, 0, 0};
      if (row < NREL) {
        float4 v = *(const float4*)(rel + i);
        o.x = f2bf(v.x); o.y = f2bf(v.y); o.z = f2bf(v.z); o.w = f2bf(v.w);
      }
      *(ushort4*)(RelB + i) = o;
    }
    return;
  }
  const float* src; ushort* dst;
  switch (blockIdx.z) {
    case 0:  src = s0; dst = d0; break;
    case 1:  src = s1; dst = d1; break;
    case 2:  src = s2; dst = d2; break;
    default: src = s3; dst = d3; break;
  }
  __shared__ float tile[32][33];
  int bx = blockIdx.x * 32, by = blockIdx.y * 32;
  int tx = threadIdx.x & 31, ty = threadIdx.x >> 5;  // ty 0..7
  #pragma unroll
  for (int i = 0; i < 32; i += 8)
    tile[ty + i][tx] = src[(size_t)(by + ty + i) * H + bx + tx];
  __syncthreads();
  #pragma unroll
  for (int i = 0; i < 32; i += 8)
    dst[(size_t)(bx + ty + i) * H + by + tx] = f2bf(tile[tx][ty + i]);
}

// ------------------------------------------------------------- bf16 MFMA GEMM
// r11-proven: BM=128 x BN=256, BK=64, single-buffer 2-barrier, 48 KB LDS,
// 256 thr (4 waves 2x2, wave tile 64x128). XOR-swizzled LDS both-sides.
__device__ __forceinline__ void gload_lds16(const void* g, void* l) {
  __builtin_amdgcn_global_load_lds(
      (const __attribute__((address_space(1))) unsigned int*)g,
      (__attribute__((address_space(3))) unsigned int*)l, 16, 0, 0);
}

#define BM 128
#define BN 256
#define BK 64
#define ATILE (BM * BK)   // 8192 ushort = 16 KB
#define BTILE (BN * BK)   // 16384 ushort = 32 KB

#define GEMM_COMPUTE()                                                         \
  _Pragma("unroll")                                                            \
  for (int kk = 0; kk < 2; ++kk) {                                             \
    const int sw = (((kk << 2) | lk) ^ (lr & 7)) * 8;                          \
    short8 af[4], bfr[8];                                                      \
    _Pragma("unroll")                                                          \
    for (int m = 0; m < 4; ++m)                                                \
      af[m] = *(const short8*)(As + (wr * 64 + m * 16 + lr) * BK + sw);        \
    _Pragma("unroll")                                                          \
    for (int n = 0; n < 8; ++n)                                                \
      bfr[n] = *(const short8*)(Bs + (wc * 128 + n * 16 + lr) * BK + sw);      \
    _Pragma("unroll")                                                          \
    for (int m = 0; m < 4; ++m)                                                \
      _Pragma("unroll")                                                        \
      for (int n = 0; n < 8; ++n)                                              \
        acc[m][n] = __builtin_amdgcn_mfma_f32_16x16x32_bf16(af[m], bfr[n],     \
                                                            acc[m][n], 0, 0, 0);\
  }

#define GEMM_EPILOGUE()                                                        \
  _Pragma("unroll")                                                            \
  for (int m = 0; m < 4; ++m) {                                                \
    _Pragma("unroll")                                                          \
    for (int n = 0; n < 8; ++n) {                                              \
      int col = col0 + wc * 128 + n * 16 + lr;                                 \
      float b = bias[col];                                                     \
      _Pragma("unroll")                                                        \
      for (int j = 0; j < 4; ++j) {                                            \
        int row = row0 + wr * 64 + m * 16 + lk * 4 + j;                        \
        C[(size_t)row * N + col] = f2bf(acc[m][n][j] + b);                     \
      }                                                                        \
    }                                                                          \
  }

// bf16-A body (OutProj, K/V tables)
__device__ __forceinline__ void gemm_body(
    ushort* As, ushort* Bs,
    const ushort* __restrict__ A,     // [M][K] bf16
    const ushort* __restrict__ Bt,    // [N][K] bf16
    const float* __restrict__ bias,
    ushort* __restrict__ C,           // [M][N] bf16
    int M, int N, int K, int bx, int by) {
  const int tid = threadIdx.x;
  const int row0 = by * BM;
  const int col0 = bx * BN;
  const int wave = tid >> 6;
  const int lane = tid & 63;
  const int wr = wave >> 1, wc = wave & 1;
  const int lr = lane & 15, lk = lane >> 4;
  f32x4 acc[4][8];
  #pragma unroll
  for (int m = 0; m < 4; ++m)
    #pragma unroll
    for (int n = 0; n < 8; ++n) acc[m][n] = (f32x4)(0.f);

  for (int k0 = 0; k0 < K; k0 += BK) {
    #pragma unroll
    for (int i = 0; i < 4; ++i) {                 // A: 1024 chunks
      int c = tid + i * 256; int r = c >> 3, s = c & 7; int gsx = s ^ (r & 7);
      gload_lds16(A + (size_t)(row0 + r) * K + k0 + gsx * 8, (char*)As + c * 16);
    }
    #pragma unroll
    for (int i = 0; i < 8; ++i) {                 // B: 2048 chunks
      int c = tid + i * 256; int r = c >> 3, s = c & 7; int gsx = s ^ (r & 7);
      gload_lds16(Bt + (size_t)(col0 + r) * K + k0 + gsx * 8, (char*)Bs + c * 16);
    }
    __syncthreads();
    GEMM_COMPUTE()
    __syncthreads();
  }
  GEMM_EPILOGUE()
}

// -------------------- K/V tables (6 blocks), launched BEFORE qattn (no race)
__global__ __launch_bounds__(256, 2) void kv_kernel(
    const ushort* __restrict__ RelB,
    const ushort* __restrict__ WkT, const float* __restrict__ bk, ushort* __restrict__ Ktab,
    const ushort* __restrict__ WvT, const float* __restrict__ bv, ushort* __restrict__ Vtab) {
  __shared__ ushort As[ATILE];
  __shared__ ushort Bs[BTILE];
  int lin = blockIdx.x;
  if (lin < 3)
    gemm_body(As, Bs, RelB, WkT, bk, Ktab, NRELP, H, H, lin, 0);
  else
    gemm_body(As, Bs, RelB, WvT, bv, Vtab, NRELP, H, H, lin - 3, 0);
}

// ---------------- fused Q-GEMM + attention: block (bx,by) owns exactly the
// (token, head) pairs its Q-tile covers. Q never touches global memory.
__global__ __launch_bounds__(256, 2) void qattn_kernel(
    const float* __restrict__ X, const ushort* __restrict__ WqT,
    const float* __restrict__ bq,
    const ushort* __restrict__ Ktab, const ushort* __restrict__ Vtab,
    const int* __restrict__ graph, const int* __restrict__ relid,
    ushort* __restrict__ Ctx) {
  __shared__ ushort As[ATILE];   // 16 KB
  __shared__ ushort Bs[BTILE];   // 32 KB; reused as Qc after the K-loop
  char* Qc = (char*)Bs;          // [128 tok][256B = 128 half-cols], ch^(t&15)
  const int tid = threadIdx.x;
  int lin = blockIdx.x;
  int wg = (lin & 7) * 48 + (lin >> 3);   // bijective XCD swizzle (384 = 48*8)
  const int bx = wg % 3, by = wg / 3;
  const int row0 = by * BM;               // token base
  const int col0 = bx * BN;
  const int wave = tid >> 6, lane = tid & 63;
  const int wr = wave >> 1, wc = wave & 1;
  const int lr = lane & 15, lk = lane >> 4;
  f32x4 acc[4][8];
  #pragma unroll
  for (int m = 0; m < 4; ++m)
    #pragma unroll
    for (int n = 0; n < 8; ++n) acc[m][n] = (f32x4)(0.f);

  for (int k0 = 0; k0 < H; k0 += BK) {
    #pragma unroll
    for (int i = 0; i < 8; ++i) {                 // B async
      int c = tid + i * 256; int r = c >> 3, s = c & 7; int gsx = s ^ (r & 7);
      gload_lds16(WqT + (size_t)(col0 + r) * H + k0 + gsx * 8, (char*)Bs + c * 16);
    }
    #pragma unroll
    for (int i = 0; i < 4; ++i) {                 // A: f32 -> bf16 -> LDS
      int c = tid + i * 256; int r = c >> 3, s = c & 7; int gsx = s ^ (r & 7);
      const float* src = X + (size_t)(row0 + r) * H + k0 + gsx * 8;
      float4 f0 = *(const float4*)(src);
      float4 f1 = *(const float4*)(src + 4);
      uint4 w;
      w.x = cvt_pk_bf16(f0.x, f0.y);
      w.y = cvt_pk_bf16(f0.z, f0.w);
      w.z = cvt_pk_bf16(f1.x, f1.y);
      w.w = cvt_pk_bf16(f1.z, f1.w);
      *(uint4*)((char*)As + c * 16) = w;
    }
    __syncthreads();
    GEMM_COMPUTE()
    __syncthreads();
  }

  // pack acc (+bq) to bf16 early: frees 128 VGPR of acc, keeps 64
  unsigned int pk[4][8][2];
  #pragma unroll
  for (int m = 0; m < 4; ++m)
    #pragma unroll
    for (int n = 0; n < 8; ++n) {
      float b = bq[col0 + wc * 128 + n * 16 + lr];
      pk[m][n][0] = cvt_pk_bf16(acc[m][n][0] + b, acc[m][n][1] + b);
      pk[m][n][1] = cvt_pk_bf16(acc[m][n][2] + b, acc[m][n][3] + b);
    }

  #pragma unroll
  for (int h2 = 0; h2 < 2; ++h2) {
    // waves with wc==h2 own cols [h2*128, h2*128+128): write Qc half
    if (wc == h2) {
      #pragma unroll
      for (int m = 0; m < 4; ++m)
        #pragma unroll
        for (int n = 0; n < 8; ++n) {
          int colc = n * 16 + lr;            // half-local 0..127
          int ch = colc >> 3;
          #pragma unroll
          for (int j = 0; j < 4; ++j) {
            int trow = wr * 64 + m * 16 + lk * 4 + j;
            unsigned int u = pk[m][n][j >> 1];
            ushort val = (j & 1) ? (ushort)(u >> 16) : (ushort)(u & 0xffffu);
            *(ushort*)(Qc + trow * 256 + ((ch ^ (trow & 15)) << 4)
                       + ((colc & 7) << 1)) = val;
          }
        }
    }
    __syncthreads();
    // attention: 256 threads -> 128 tokens x 2 heads of this half
    {
      const int hh = tid & 1, t = tid >> 1;
      const int head = bx * 4 + h2 * 2 + hh;
      const int gtok = row0 + t;
      uint4 qw[8];
      #pragma unroll
      for (int k = 0; k < 8; ++k)
        qw[k] = *(const uint4*)(Qc + t * 256 + ((((hh << 3) | k) ^ (t & 15)) << 4));
      const int4* gp = (const int4*)(graph + (size_t)gtok * LL);
      const int4* rp = (const int4*)(relid + (size_t)gtok * LL);
      int4 ga = gp[0], gb = gp[1];
      int4 ra = rp[0], rb = rp[1];
      int gs[8] = {ga.x, ga.y, ga.z, ga.w, gb.x, gb.y, gb.z, gb.w};
      int rid[8] = {ra.x, ra.y, ra.z, ra.w, rb.x, rb.y, rb.z, rb.w};
      size_t koff[8];
      #pragma unroll
      for (int l = 0; l < 8; ++l) {
        int r = rid[l] < 0 ? 0 : rid[l];
        koff[l] = (size_t)r * H + head * DH;
      }
      float s[8];
      #pragma unroll
      for (int l = 0; l < 8; ++l) s[l] = 0.f;
      #pragma unroll
      for (int j = 0; j < 8; ++j) {
        float qf[8];
        qf[0] = bflo(qw[j].x); qf[1] = bfhi(qw[j].x);
        qf[2] = bflo(qw[j].y); qf[3] = bfhi(qw[j].y);
        qf[4] = bflo(qw[j].z); qf[5] = bfhi(qw[j].z);
        qf[6] = bflo(qw[j].w); qf[7] = bfhi(qw[j].w);
        #pragma unroll
        for (int l = 0; l < 8; ++l) {
          uint4 kw = *(const uint4*)(Ktab + koff[l] + j * 8);
          s[l] += qf[0] * bflo(kw.x) + qf[1] * bfhi(kw.x)
                + qf[2] * bflo(kw.y) + qf[3] * bfhi(kw.y)
                + qf[4] * bflo(kw.z) + qf[5] * bfhi(kw.z)
                + qf[6] * bflo(kw.w) + qf[7] * bfhi(kw.w);
        }
      }
      #pragma unroll
      for (int l = 0; l < 8; ++l)
        s[l] = (gs[l] != -1) ? s[l] * 0.125f : -10000.0f;
      float mx = s[0];
      #pragma unroll
      for (int l = 1; l < 8; ++l) mx = fmaxf(mx, s[l]);
      float p[8], den = 0.f;
      #pragma unroll
      for (int l = 0; l < 8; ++l) { p[l] = __expf(s[l] - mx); den += p[l]; }
      float inv = 1.f / den;
      #pragma unroll
      for (int l = 0; l < 8; ++l) p[l] *= inv;
      ushort* cp = Ctx + (size_t)gtok * H + head * DH;
      #pragma unroll
      for (int j = 0; j < 8; ++j) {
        float a[8];
        #pragma unroll
        for (int d = 0; d < 8; ++d) a[d] = 0.f;
        #pragma unroll
        for (int l = 0; l < 8; ++l) {
          uint4 vw = *(const uint4*)(Vtab + koff[l] + j * 8);
          a[0] += p[l] * bflo(vw.x); a[1] += p[l] * bfhi(vw.x);
          a[2] += p[l] * bflo(vw.y); a[3] += p[l] * bfhi(vw.y);
          a[4] += p[l] * bflo(vw.z); a[5] += p[l] * bfhi(vw.z);
          a[6] += p[l] * bflo(vw.w); a[7] += p[l] * bfhi(vw.w);
        }
        short8 o;
        #pragma unroll
        for (int d = 0; d < 8; ++d) o[d] = (short)f2bf(a[d]);
        *(short8*)(cp + j * 8) = o;
      }
    }
    __syncthreads();   // Qc reads done before next half overwrites
  }
}

// big bf16 GEMM (OutProj): XCD-swizzled grid (3 x 128)
__global__ __launch_bounds__(256, 2) void gemm_bt_kernel(
    const ushort* __restrict__ A, const ushort* __restrict__ Bt,
    const float* __restrict__ bias, ushort* __restrict__ C,
    int M, int N, int K) {
  __shared__ ushort As[ATILE];
  __shared__ ushort Bs[BTILE];
  int lin = blockIdx.y * gridDim.x + blockIdx.x;
  int q = (gridDim.x * gridDim.y) >> 3;
  int wg = (lin & 7) * q + (lin >> 3);
  gemm_body(As, Bs, A, Bt, bias, C, M, N, K, wg % gridDim.x, wg / gridDim.x);
}

// ------------------------------------- residual + LayerNorm (192 thr, float4)
__global__ __launch_bounds__(192) void ln_kernel(
    const float* __restrict__ text, const ushort* __restrict__ op,
    const float* __restrict__ gamma, const float* __restrict__ beta,
    float* __restrict__ out) {
  int t = blockIdx.x;
  int c0 = threadIdx.x * 4;
  float4 tv = *(const float4*)(text + (size_t)t * H + c0);
  ushort4 ov = *(const ushort4*)(op + (size_t)t * H + c0);
  float x0 = tv.x + bf2f(ov.x), x1 = tv.y + bf2f(ov.y);
  float x2 = tv.z + bf2f(ov.z), x3 = tv.w + bf2f(ov.w);
  float s = x0 + x1 + x2 + x3;
  float s2 = x0 * x0 + x1 * x1 + x2 * x2 + x3 * x3;
  #pragma unroll
  for (int off = 32; off > 0; off >>= 1) {
    s  += __shfl_xor(s, off, 64);
    s2 += __shfl_xor(s2, off, 64);
  }
  __shared__ float red[2][3];
  int wave = threadIdx.x >> 6, lane = threadIdx.x & 63;
  if (lane == 0) { red[0][wave] = s; red[1][wave] = s2; }
  __syncthreads();
  s  = red[0][0] + red[0][1] + red[0][2];
  s2 = red[1][0] + red[1][1] + red[1][2];
  float mu = s * (1.f / H);
  float var = s2 * (1.f / H) - mu * mu;
  float rs = rsqrtf(var + 1e-5f);
  float4 g4 = *(const float4*)(gamma + c0);
  float4 b4 = *(const float4*)(beta + c0);
  float4 o4;
  o4.x = (x0 - mu) * rs * g4.x + b4.x;
  o4.y = (x1 - mu) * rs * g4.y + b4.y;
  o4.z = (x2 - mu) * rs * g4.z + b4.z;
  o4.w = (x3 - mu) * rs * g4.w + b4.w;
  *(float4*)(out + (size_t)t * H + c0) = o4;
}

// ---------------------------------------------------------------------- driver
extern "C" void kernel_launch(void* const* d_in, const int* in_sizes, int n_in,
                              void* d_out, int out_size, void* d_ws, size_t ws_size,
                              hipStream_t stream) {
  const float* text      = (const float*)d_in[0];
  const int*   graph     = (const int*)d_in[1];
  const int*   relid     = (const int*)d_in[2];
  const float* rel_table = (const float*)d_in[3];
  const float* Wq = (const float*)d_in[4];  const float* bq = (const float*)d_in[5];
  const float* Wk = (const float*)d_in[6];  const float* bk = (const float*)d_in[7];
  const float* Wv = (const float*)d_in[8];  const float* bv = (const float*)d_in[9];
  const float* Wo = (const float*)d_in[10]; const float* bo = (const float*)d_in[11];
  const float* gamma = (const float*)d_in[12];
  const float* beta  = (const float*)d_in[13];
  float* out = (float*)d_out;
  char* ws = (char*)d_ws;

  const size_t TOKH = (size_t)NTOK * H;           // 12,582,912
  size_t off = 0;
  ushort* Ctx  = (ushort*)(ws + off); off += TOKH * 2;             // attn out
  ushort* OP   = (ushort*)(ws + off); off += TOKH * 2;             // OutProj out
  ushort* WqT  = (ushort*)(ws + off); off += (size_t)H * H * 2;
  ushort* WoT  = (ushort*)(ws + off); off += (size_t)H * H * 2;
  ushort* WkT  = (ushort*)(ws + off); off += (size_t)H * H * 2;
  ushort* WvT  = (ushort*)(ws + off); off += (size_t)H * H * 2;
  ushort* RelB = (ushort*)(ws + off); off += (size_t)NRELP * H * 2;
  ushort* Ktab = (ushort*)(ws + off); off += (size_t)NRELP * H * 2;
  ushort* Vtab = (ushort*)(ws + off); off += (size_t)NRELP * H * 2;

  // 1) weight transposes + rel_table cvt
  prep_kernel<<<dim3(24, 24, 5), 256, 0, stream>>>(
      Wq, WqT, Wo, WoT, Wk, WkT, Wv, WvT, rel_table, RelB);
  // 2) K/V tables (6 blocks) — completes before qattn (separate launch)
  kv_kernel<<<6, 256, 0, stream>>>(RelB, WkT, bk, Ktab, WvT, bv, Vtab);
  // 3) fused Q-GEMM + attention -> Ctx (384 blocks, XCD-swizzled)
  qattn_kernel<<<384, 256, 0, stream>>>(
      text, WqT, bq, Ktab, Vtab, graph, relid, Ctx);
  // 4) OutProj = Ctx @ WoT^T + bo
  dim3 g1(H / BN, NTOK / BM);
  gemm_bt_kernel<<<g1, 256, 0, stream>>>(Ctx, WoT, bo, OP, NTOK, H, H);
  // 5) residual + LayerNorm -> out
  ln_kernel<<<NTOK, 192, 0, stream>>>(text, OP, gamma, beta, out);
}

// Round 15
// 101.736 us; speedup vs baseline: 1.9402x; 1.6269x over previous
//
#include <hip/hip_runtime.h>
#include <hip/hip_bf16.h>

#define H 768
#define NH 12
#define DH 64
#define LL 8
#define NTOK 16384   // B*S = 8*2048
#define NREL 100
#define NRELP 128    // padded rows for the K/V-table GEMM
#define PADW 72      // attn LDS row stride in bf16 (144 B = 9 x 16B chunks)

typedef __attribute__((ext_vector_type(8))) short short8;
typedef __attribute__((ext_vector_type(4))) float f32x4;

__device__ __forceinline__ float bf2f(ushort u) {
  union { unsigned int i; float f; } v; v.i = ((unsigned int)u) << 16; return v.f;
}
__device__ __forceinline__ float bflo(unsigned int u) {
  union { unsigned int i; float f; } v; v.i = u << 16; return v.f;
}
__device__ __forceinline__ float bfhi(unsigned int u) {
  union { unsigned int i; float f; } v; v.i = u & 0xffff0000u; return v.f;
}
__device__ __forceinline__ ushort f2bf(float f) {
  union { float f; unsigned int i; } v; v.f = f;
  unsigned int x = v.i;
  return (ushort)((x + 0x7fffu + ((x >> 16) & 1u)) >> 16);  // RNE
}
// HW packed f32->bf16 (RNE); lo = S0, hi = S1 [guide T12 recipe, m214v22]
__device__ __forceinline__ unsigned int cvt_pk_bf16(float lo, float hi) {
  unsigned int r;
  asm("v_cvt_pk_bf16_f32 %0, %1, %2" : "=v"(r) : "v"(lo), "v"(hi));
  return r;
}

// ---------- prep: z<4 -> weight transpose [H][H] f32->bf16; z=4 -> rel cvt
__global__ __launch_bounds__(256) void prep_kernel(
    const float* __restrict__ s0, ushort* __restrict__ d0,
    const float* __restrict__ s1, ushort* __restrict__ d1,
    const float* __restrict__ s2, ushort* __restrict__ d2,
    const float* __restrict__ s3, ushort* __restrict__ d3,
    const float* __restrict__ rel, ushort* __restrict__ RelB) {
  if (blockIdx.z == 4) {
    int b = blockIdx.y * 24 + blockIdx.x;
    if (b < 96) {                                  // 96*1024 = NRELP*H
      int i = (b * 256 + threadIdx.x) * 4;         // 4-chunk stays within a row
      int row = i / H;
      ushort4 o = {0, 0, 0, 0};
      if (row < NREL) {
        float4 v = *(const float4*)(rel + i);
        o.x = f2bf(v.x); o.y = f2bf(v.y); o.z = f2bf(v.z); o.w = f2bf(v.w);
      }
      *(ushort4*)(RelB + i) = o;
    }
    return;
  }
  const float* src; ushort* dst;
  switch (blockIdx.z) {
    case 0:  src = s0; dst = d0; break;
    case 1:  src = s1; dst = d1; break;
    case 2:  src = s2; dst = d2; break;
    default: src = s3; dst = d3; break;
  }
  __shared__ float tile[32][33];
  int bx = blockIdx.x * 32, by = blockIdx.y * 32;
  int tx = threadIdx.x & 31, ty = threadIdx.x >> 5;  // ty 0..7
  #pragma unroll
  for (int i = 0; i < 32; i += 8)
    tile[ty + i][tx] = src[(size_t)(by + ty + i) * H + bx + tx];
  __syncthreads();
  #pragma unroll
  for (int i = 0; i < 32; i += 8)
    dst[(size_t)(bx + ty + i) * H + by + tx] = f2bf(tile[tx][ty + i]);
}

// ------------------------------------------------------------- bf16 MFMA GEMM
// C[M][N] = A[M][K] @ Bt[N][K]^T + bias. BM=128 x BN=256, BK=64 — single-buffer
// 2-barrier skeleton, 48 KB LDS: 64 MFMA/wave/K-step amortize the fixed
// per-barrier stage-drain stall. XOR-swizzled LDS (T2 both-sides): physical
// 16B slot s of row r holds logical k-segment s^(r&7); ds_read applies the
// same involution.
__device__ __forceinline__ void gload_lds16(const void* g, void* l) {
  __builtin_amdgcn_global_load_lds(
      (const __attribute__((address_space(1))) unsigned int*)g,
      (__attribute__((address_space(3))) unsigned int*)l, 16, 0, 0);
}

#define BM 128
#define BN 256
#define BK 64
#define ATILE (BM * BK)   // 8192 ushort = 16 KB
#define BTILE (BN * BK)   // 16384 ushort = 32 KB

// waves 2x2 over 128x256: wave rows wr*64, cols wc*128; acc[4][8]
#define GEMM_COMPUTE()                                                         \
  _Pragma("unroll")                                                            \
  for (int kk = 0; kk < 2; ++kk) {                                             \
    const int sw = (((kk << 2) | lk) ^ (lr & 7)) * 8;                          \
    short8 af[4], bfr[8];                                                      \
    _Pragma("unroll")                                                          \
    for (int m = 0; m < 4; ++m)                                                \
      af[m] = *(const short8*)(As + (wr * 64 + m * 16 + lr) * BK + sw);        \
    _Pragma("unroll")                                                          \
    for (int n = 0; n < 8; ++n)                                                \
      bfr[n] = *(const short8*)(Bs + (wc * 128 + n * 16 + lr) * BK + sw);      \
    _Pragma("unroll")                                                          \
    for (int m = 0; m < 4; ++m)                                                \
      _Pragma("unroll")                                                        \
      for (int n = 0; n < 8; ++n)                                              \
        acc[m][n] = __builtin_amdgcn_mfma_f32_16x16x32_bf16(af[m], bfr[n],     \
                                                            acc[m][n], 0, 0, 0);\
  }

#define GEMM_EPILOGUE()                                                        \
  _Pragma("unroll")                                                            \
  for (int m = 0; m < 4; ++m) {                                                \
    _Pragma("unroll")                                                          \
    for (int n = 0; n < 8; ++n) {                                              \
      int col = col0 + wc * 128 + n * 16 + lr;                                 \
      float b = bias[col];                                                     \
      _Pragma("unroll")                                                        \
      for (int j = 0; j < 4; ++j) {                                            \
        int row = row0 + wr * 64 + m * 16 + lk * 4 + j;                        \
        C[(size_t)row * N + col] = f2bf(acc[m][n][j] + b);                     \
      }                                                                        \
    }                                                                          \
  }

// bf16-A variant (OutProj, K/V tables)
__device__ __forceinline__ void gemm_body(
    ushort* As, ushort* Bs,
    const ushort* __restrict__ A,     // [M][K] bf16
    const ushort* __restrict__ Bt,    // [N][K] bf16
    const float* __restrict__ bias,
    ushort* __restrict__ C,           // [M][N] bf16
    int M, int N, int K, int bx, int by) {
  const int tid = threadIdx.x;
  const int row0 = by * BM;
  const int col0 = bx * BN;
  const int wave = tid >> 6;
  const int lane = tid & 63;
  const int wr = wave >> 1, wc = wave & 1;
  const int lr = lane & 15, lk = lane >> 4;
  f32x4 acc[4][8];
  #pragma unroll
  for (int m = 0; m < 4; ++m)
    #pragma unroll
    for (int n = 0; n < 8; ++n) acc[m][n] = (f32x4)(0.f);

  for (int k0 = 0; k0 < K; k0 += BK) {
    #pragma unroll
    for (int i = 0; i < 4; ++i) {                 // A: 1024 chunks
      int c = tid + i * 256; int r = c >> 3, s = c & 7; int gsx = s ^ (r & 7);
      gload_lds16(A + (size_t)(row0 + r) * K + k0 + gsx * 8, (char*)As + c * 16);
    }
    #pragma unroll
    for (int i = 0; i < 8; ++i) {                 // B: 2048 chunks
      int c = tid + i * 256; int r = c >> 3, s = c & 7; int gsx = s ^ (r & 7);
      gload_lds16(Bt + (size_t)(col0 + r) * K + k0 + gsx * 8, (char*)Bs + c * 16);
    }
    __syncthreads();
    GEMM_COMPUTE()
    __syncthreads();
  }
  GEMM_EPILOGUE()
}

// A-side = f32 source (fused X->bf16 cvt): reg-stage + cvt_pk + linear ds_write
__device__ __forceinline__ void gemm_body_a32(
    ushort* As, ushort* Bs,
    const float* __restrict__ A32,    // [M][K] f32
    const ushort* __restrict__ Bt,    // [N][K] bf16
    const float* __restrict__ bias,
    ushort* __restrict__ C,
    int M, int N, int K, int bx, int by) {
  const int tid = threadIdx.x;
  const int row0 = by * BM;
  const int col0 = bx * BN;
  const int wave = tid >> 6;
  const int lane = tid & 63;
  const int wr = wave >> 1, wc = wave & 1;
  const int lr = lane & 15, lk = lane >> 4;
  f32x4 acc[4][8];
  #pragma unroll
  for (int m = 0; m < 4; ++m)
    #pragma unroll
    for (int n = 0; n < 8; ++n) acc[m][n] = (f32x4)(0.f);

  for (int k0 = 0; k0 < K; k0 += BK) {
    #pragma unroll
    for (int i = 0; i < 8; ++i) {                 // B async
      int c = tid + i * 256; int r = c >> 3, s = c & 7; int gsx = s ^ (r & 7);
      gload_lds16(Bt + (size_t)(col0 + r) * K + k0 + gsx * 8, (char*)Bs + c * 16);
    }
    #pragma unroll
    for (int i = 0; i < 4; ++i) {                 // A: f32 -> bf16 -> LDS
      int c = tid + i * 256; int r = c >> 3, s = c & 7; int gsx = s ^ (r & 7);
      const float* src = A32 + (size_t)(row0 + r) * K + k0 + gsx * 8;
      float4 f0 = *(const float4*)(src);
      float4 f1 = *(const float4*)(src + 4);
      uint4 w;
      w.x = cvt_pk_bf16(f0.x, f0.y);
      w.y = cvt_pk_bf16(f0.z, f0.w);
      w.z = cvt_pk_bf16(f1.x, f1.y);
      w.w = cvt_pk_bf16(f1.z, f1.w);
      *(uint4*)((char*)As + c * 16) = w;
    }
    __syncthreads();
    GEMM_COMPUTE()
    __syncthreads();
  }
  GEMM_EPILOGUE()
}

// ---- combined launch: blocks 0..5 = K/V-table GEMMs (hidden under Q-GEMM),
//      blocks 6..389 = Q = X(f32) @ WqT^T, XCD-swizzled (384 % 8 == 0)
__global__ __launch_bounds__(256, 2) void gemm_q_kv_kernel(
    const float* __restrict__ X, const ushort* __restrict__ WqT,
    const float* __restrict__ bq, ushort* __restrict__ Qbf,
    const ushort* __restrict__ RelB,
    const ushort* __restrict__ WkT, const float* __restrict__ bk, ushort* __restrict__ Ktab,
    const ushort* __restrict__ WvT, const float* __restrict__ bv, ushort* __restrict__ Vtab) {
  __shared__ ushort As[ATILE];   // 16 KB
  __shared__ ushort Bs[BTILE];   // 32 KB
  int lin = blockIdx.x;
  if (lin < 6) {
    if (lin < 3)
      gemm_body(As, Bs, RelB, WkT, bk, Ktab, NRELP, H, H, lin, 0);
    else
      gemm_body(As, Bs, RelB, WvT, bv, Vtab, NRELP, H, H, lin - 3, 0);
    return;
  }
  int l2 = lin - 6;                         // 0..383
  int wg = (l2 & 7) * 48 + (l2 >> 3);       // bijective XCD swizzle (384 = 48*8)
  gemm_body_a32(As, Bs, X, WqT, bq, Qbf, NTOK, H, H, wg % 3, wg / 3);
}

// big bf16 GEMM (OutProj): XCD-swizzled grid (3 x 128)
__global__ __launch_bounds__(256, 2) void gemm_bt_kernel(
    const ushort* __restrict__ A, const ushort* __restrict__ Bt,
    const float* __restrict__ bias, ushort* __restrict__ C,
    int M, int N, int K) {
  __shared__ ushort As[ATILE];
  __shared__ ushort Bs[BTILE];
  int lin = blockIdx.y * gridDim.x + blockIdx.x;
  int q = (gridDim.x * gridDim.y) >> 3;
  int wg = (lin & 7) * q + (lin >> 3);
  gemm_body(As, Bs, A, Bt, bias, C, M, N, K, wg % gridDim.x, wg / gridDim.x);
}

// ---------------------------------------------- gather-form GAT attention (v3)
// One lane per (token, head). K/V head-slices staged once per block in LDS
// (rows 0..99, stride 72 bf16). Zero cross-lane ops, one barrier.
__global__ __launch_bounds__(256) void attn3_kernel(
    const ushort* __restrict__ Q,     // [NTOK][H] bf16
    const ushort* __restrict__ Ktab,  // [NRELP][H] bf16
    const ushort* __restrict__ Vtab,  // [NRELP][H] bf16
    const int* __restrict__ graph,    // [NTOK][LL]
    const int* __restrict__ relid,    // [NTOK][LL]
    ushort* __restrict__ Ctx) {       // [NTOK][H] bf16
  __shared__ __align__(16) ushort Ks[NREL * PADW];  // 14.4 KB
  __shared__ __align__(16) ushort Vs[NREL * PADW];  // 14.4 KB
  const int tid = threadIdx.x;
  const int head = blockIdx.y;
  const int t = blockIdx.x * 256 + tid;

  #pragma unroll
  for (int i = 0; i < 4; ++i) {
    int c = tid + i * 256;
    if (c < NREL * 9) {
      int row = c / 9, slot = c - row * 9;
      int gsx = (slot < 8) ? slot * 8 : 0;       // pad chunk: safe dup
      const size_t src = (size_t)row * H + head * DH + gsx;
      gload_lds16(Ktab + src, (char*)Ks + (size_t)c * 16);
      gload_lds16(Vtab + src, (char*)Vs + (size_t)c * 16);
    }
  }

  const uint4* qp = (const uint4*)(Q + (size_t)t * H + head * DH);
  uint4 qw[8];
  #pragma unroll
  for (int j = 0; j < 8; ++j) qw[j] = qp[j];
  const int4* gp = (const int4*)(graph + (size_t)t * LL);
  const int4* rp = (const int4*)(relid + (size_t)t * LL);
  int4 ga = gp[0], gb = gp[1];
  int4 ra = rp[0], rb = rp[1];
  int gs[8] = {ga.x, ga.y, ga.z, ga.w, gb.x, gb.y, gb.z, gb.w};
  int rid[8] = {ra.x, ra.y, ra.z, ra.w, rb.x, rb.y, rb.z, rb.w};
  int koff[8];
  #pragma unroll
  for (int l = 0; l < 8; ++l) {
    int r = rid[l] < 0 ? 0 : rid[l];
    koff[l] = r * (PADW * 2);
  }

  __syncthreads();

  float s[8];
  #pragma unroll
  for (int l = 0; l < 8; ++l) s[l] = 0.f;
  #pragma unroll
  for (int j = 0; j < 8; ++j) {
    float qf[8];
    qf[0] = bflo(qw[j].x); qf[1] = bfhi(qw[j].x);
    qf[2] = bflo(qw[j].y); qf[3] = bfhi(qw[j].y);
    qf[4] = bflo(qw[j].z); qf[5] = bfhi(qw[j].z);
    qf[6] = bflo(qw[j].w); qf[7] = bfhi(qw[j].w);
    #pragma unroll
    for (int l = 0; l < 8; ++l) {
      uint4 kw = *(const uint4*)((const char*)Ks + koff[l] + j * 16);
      s[l] += qf[0] * bflo(kw.x) + qf[1] * bfhi(kw.x)
            + qf[2] * bflo(kw.y) + qf[3] * bfhi(kw.y)
            + qf[4] * bflo(kw.z) + qf[5] * bfhi(kw.z)
            + qf[6] * bflo(kw.w) + qf[7] * bfhi(kw.w);
    }
  }

  #pragma unroll
  for (int l = 0; l < 8; ++l)
    s[l] = (gs[l] != -1) ? s[l] * 0.125f : -10000.0f;
  float mx = s[0];
  #pragma unroll
  for (int l = 1; l < 8; ++l) mx = fmaxf(mx, s[l]);
  float p[8], den = 0.f;
  #pragma unroll
  for (int l = 0; l < 8; ++l) { p[l] = __expf(s[l] - mx); den += p[l]; }
  float inv = 1.f / den;
  #pragma unroll
  for (int l = 0; l < 8; ++l) p[l] *= inv;

  ushort* cp = Ctx + (size_t)t * H + head * DH;
  #pragma unroll
  for (int j = 0; j < 8; ++j) {
    float a[8];
    #pragma unroll
    for (int d = 0; d < 8; ++d) a[d] = 0.f;
    #pragma unroll
    for (int l = 0; l < 8; ++l) {
      uint4 vw = *(const uint4*)((const char*)Vs + koff[l] + j * 16);
      a[0] += p[l] * bflo(vw.x); a[1] += p[l] * bfhi(vw.x);
      a[2] += p[l] * bflo(vw.y); a[3] += p[l] * bfhi(vw.y);
      a[4] += p[l] * bflo(vw.z); a[5] += p[l] * bfhi(vw.z);
      a[6] += p[l] * bflo(vw.w); a[7] += p[l] * bfhi(vw.w);
    }
    short8 o;
    #pragma unroll
    for (int d = 0; d < 8; ++d) o[d] = (short)f2bf(a[d]);
    *(short8*)(cp + j * 8) = o;
  }
}

// ------------------------------------- residual + LayerNorm (192 thr, float4)
__global__ __launch_bounds__(192) void ln_kernel(
    const float* __restrict__ text, const ushort* __restrict__ op,
    const float* __restrict__ gamma, const float* __restrict__ beta,
    float* __restrict__ out) {
  int t = blockIdx.x;
  int c0 = threadIdx.x * 4;
  float4 tv = *(const float4*)(text + (size_t)t * H + c0);
  ushort4 ov = *(const ushort4*)(op + (size_t)t * H + c0);
  float x0 = tv.x + bf2f(ov.x), x1 = tv.y + bf2f(ov.y);
  float x2 = tv.z + bf2f(ov.z), x3 = tv.w + bf2f(ov.w);
  float s = x0 + x1 + x2 + x3;
  float s2 = x0 * x0 + x1 * x1 + x2 * x2 + x3 * x3;
  #pragma unroll
  for (int off = 32; off > 0; off >>= 1) {
    s  += __shfl_xor(s, off, 64);
    s2 += __shfl_xor(s2, off, 64);
  }
  __shared__ float red[2][3];
  int wave = threadIdx.x >> 6, lane = threadIdx.x & 63;
  if (lane == 0) { red[0][wave] = s; red[1][wave] = s2; }
  __syncthreads();
  s  = red[0][0] + red[0][1] + red[0][2];
  s2 = red[1][0] + red[1][1] + red[1][2];
  float mu = s * (1.f / H);
  float var = s2 * (1.f / H) - mu * mu;
  float rs = rsqrtf(var + 1e-5f);
  float4 g4 = *(const float4*)(gamma + c0);
  float4 b4 = *(const float4*)(beta + c0);
  float4 o4;
  o4.x = (x0 - mu) * rs * g4.x + b4.x;
  o4.y = (x1 - mu) * rs * g4.y + b4.y;
  o4.z = (x2 - mu) * rs * g4.z + b4.z;
  o4.w = (x3 - mu) * rs * g4.w + b4.w;
  *(float4*)(out + (size_t)t * H + c0) = o4;
}

// ---------------------------------------------------------------------- driver
extern "C" void kernel_launch(void* const* d_in, const int* in_sizes, int n_in,
                              void* d_out, int out_size, void* d_ws, size_t ws_size,
                              hipStream_t stream) {
  const float* text      = (const float*)d_in[0];
  const int*   graph     = (const int*)d_in[1];
  const int*   relid     = (const int*)d_in[2];
  const float* rel_table = (const float*)d_in[3];
  const float* Wq = (const float*)d_in[4];  const float* bq = (const float*)d_in[5];
  const float* Wk = (const float*)d_in[6];  const float* bk = (const float*)d_in[7];
  const float* Wv = (const float*)d_in[8];  const float* bv = (const float*)d_in[9];
  const float* Wo = (const float*)d_in[10]; const float* bo = (const float*)d_in[11];
  const float* gamma = (const float*)d_in[12];
  const float* beta  = (const float*)d_in[13];
  float* out = (float*)d_out;
  char* ws = (char*)d_ws;

  const size_t TOKH = (size_t)NTOK * H;           // 12,582,912
  size_t off = 0;
  ushort* Ctx  = (ushort*)(ws + off); off += TOKH * 2;             // attn out
  ushort* Qbf  = (ushort*)(ws + off); off += TOKH * 2;             // Q, reused as OutProj
  ushort* WqT  = (ushort*)(ws + off); off += (size_t)H * H * 2;
  ushort* WoT  = (ushort*)(ws + off); off += (size_t)H * H * 2;
  ushort* WkT  = (ushort*)(ws + off); off += (size_t)H * H * 2;
  ushort* WvT  = (ushort*)(ws + off); off += (size_t)H * H * 2;
  ushort* RelB = (ushort*)(ws + off); off += (size_t)NRELP * H * 2;
  ushort* Ktab = (ushort*)(ws + off); off += (size_t)NRELP * H * 2;
  ushort* Vtab = (ushort*)(ws + off); off += (size_t)NRELP * H * 2;

  // 1) weight transposes + rel_table cvt (one launch)
  prep_kernel<<<dim3(24, 24, 5), 256, 0, stream>>>(
      Wq, WqT, Wo, WoT, Wk, WkT, Wv, WvT, rel_table, RelB);
  // 2) Q = X(f32) @ WqT^T + bq  (fused cvt), with K/V-table GEMMs hidden inside
  gemm_q_kv_kernel<<<6 + 384, 256, 0, stream>>>(
      text, WqT, bq, Qbf, RelB, WkT, bk, Ktab, WvT, bv, Vtab);
  // 3) attention -> Ctx
  dim3 ga(NTOK / 256, NH);
  attn3_kernel<<<ga, 256, 0, stream>>>(Qbf, Ktab, Vtab, graph, relid, Ctx);
  // 4) OutProj = Ctx @ WoT^T + bo (reuse Qbf storage)
  dim3 g1(H / BN, NTOK / BM);
  gemm_bt_kernel<<<g1, 256, 0, stream>>>(Ctx, WoT, bo, Qbf, NTOK, H, H);
  // 5) residual + LayerNorm -> out
  ln_kernel<<<NTOK, 192, 0, stream>>>(text, Qbf, gamma, beta, out);
}